// Round 12
// baseline (2768.036 us; speedup 1.0000x reference)
//
#include <hip/hip_runtime.h>
#include <hip/hip_fp16.h>
#include <stdint.h>

#define RES 8192
#define TSTEPS 512
#define NB 256
#define NT 512
#define ROWS_PER_BLOCK 32
#define LPR 16                           // lanes per row
#define SLOTS 72                         // 64 aligned (2 bank-rings) + 8 tail
#define PW_ITERS (SLOTS / 4)             // 18 uint4 per lane
#define ROW_DW (SLOTS * LPR)             // 1152 dwords per packed row

typedef uint32_t u32x4 __attribute__((ext_vector_type(4)));

// workspace layout (bytes)
#define WS_PACKED_OFF   0u
#define WS_PAIRS_OFF    37748736u                    // 8192*1152*4
#define WS_TAGS_OFF     46153728u                    // + 513*4096*4
#define TAGS_BYTES      525312u                      // 513*256*4

__device__ __forceinline__ float2 unpack_h2(uint32_t u) {
    __half2 h = *reinterpret_cast<__half2*>(&u);
    return __half22float2(h);
}

// entry encoding: e = (val19 << 13) | col13, bank = col & 31.
// decode: val = as_float(e) (13 low mantissa bits are col-garbage, rel err 2^-10), idx = e & 8191
__global__ __launch_bounds__(256) void esn_compress(const float* __restrict__ W,
                                                    uint32_t* __restrict__ packed) {
    __shared__ uint32_t lst[4][1024];
    __shared__ uint32_t grid[4][LPR][SLOTS];
    __shared__ uint32_t ovf[4][32][28];
    __shared__ unsigned ovfn[4][32];
    __shared__ unsigned tbase_s[4][32];

    const int wave = threadIdx.x >> 6;
    const int lane = threadIdx.x & 63;
    const int row  = blockIdx.x * 4 + wave;
    const float* wrow = W + (size_t)row * RES;
    uint32_t* prow = packed + (size_t)row * ROW_DW;

    // ---- pass 1: compact nonzeros ----
    unsigned nnz = 0;
    for (int chunk = 0; chunk < RES / 64; ++chunk) {
        const int c = chunk * 64 + lane;
        const float v = wrow[c];
        const bool nz = (v != 0.0f);
        const unsigned long long m = __ballot(nz);
        if (nz) {
            unsigned pos = nnz + (unsigned)__popcll(m & ((1ull << lane) - 1ull));
            if (pos < 1024u) {
                uint32_t b = (__float_as_uint(v) + 0x1000u) & 0xFFFFE000u;
                lst[wave][pos] = b | (uint32_t)c;
            }
        }
        nnz += (unsigned)__popcll(m);
    }
    if (nnz > 1024u) nnz = 1024u;

    // ---- prefill grid with bank-correct pads (val=0 denormal) ----
    for (int d = lane; d < LPR * SLOTS; d += 64) {
        const int li = d / SLOTS;
        const int sl = d % SLOTS;
        const unsigned rot = (((unsigned)row & 1u) << 4) | (unsigned)li;
        grid[wave][li][sl] = (sl < 64) ? ((rot + (unsigned)sl) & 31u) : 0u;
    }
    __syncthreads();

    // ---- single scan: place aligned entries; collect overflow per bank ----
    if (lane < 32) {
        const unsigned b = (unsigned)lane;
        unsigned i = 0, ov = 0;
        for (unsigned idx = 0; idx < nnz; ++idx) {
            const uint32_t e = lst[wave][idx];
            if ((e & 31u) == b) {
                if (i < 32u) {
                    const unsigned li = i & 15u;
                    const unsigned j  = i >> 4;
                    const unsigned rot = (((unsigned)row & 1u) << 4) | li;
                    const unsigned s = j * 32u + ((b - rot) & 31u);
                    grid[wave][li][s] = e;
                } else if (ov < 28u) {
                    ovf[wave][b][ov] = e;
                    ++ov;
                }
                ++i;
            }
        }
        ovfn[wave][b] = ov;
    }
    __syncthreads();
    if (lane == 0) {
        unsigned run = 0;
        for (int b2 = 0; b2 < 32; ++b2) { tbase_s[wave][b2] = run; run += ovfn[wave][b2]; }
    }
    __syncthreads();
    if (lane < 32) {
        const unsigned b = (unsigned)lane;
        const unsigned tb = tbase_s[wave][b];
        const unsigned ov = ovfn[wave][b];
        for (unsigned j = 0; j < ov; ++j) {
            const unsigned q = tb + j;
            if (q < 128u) grid[wave][q & 15u][64u + (q >> 4)] = ovf[wave][b][j];
        }
    }
    __syncthreads();

    // ---- write out; reader maps uint4 #i, lane li, comp c -> slot 4i+c ----
    for (int d = lane; d < ROW_DW; d += 64) {
        const int li = (d & 63) >> 2;
        const int sl = ((d >> 6) << 2) | (d & 3);
        prow[d] = grid[wave][li][sl];
    }
}

// bulk fp16-pair stage (plain, post-detect): 2 x dwordx4 per thread = full h
__device__ __forceinline__ void stage_pairs(const uint32_t* __restrict__ pb,
                                            int tid, float* lds_h) {
    const uint32_t* pa = pb + 4 * tid;
    const uint32_t* pc = pb + 2048 + 4 * tid;
    u32x4 a, b;
    asm volatile("global_load_dwordx4 %0, %2, off sc0 sc1\n\t"
                 "global_load_dwordx4 %1, %3, off sc0 sc1\n\t"
                 "s_waitcnt vmcnt(0)"
                 : "=&v"(a), "=&v"(b) : "v"(pa), "v"(pc) : "memory");
    float4* const lds4 = (float4*)lds_h;
    {
        const float2 f0 = unpack_h2(a.x), f1 = unpack_h2(a.y);
        const float2 f2 = unpack_h2(a.z), f3 = unpack_h2(a.w);
        lds4[2 * tid + 0] = make_float4(f0.x, f0.y, f1.x, f1.y);
        lds4[2 * tid + 1] = make_float4(f2.x, f2.y, f3.x, f3.y);
    }
    {
        const float2 f0 = unpack_h2(b.x), f1 = unpack_h2(b.y);
        const float2 f2 = unpack_h2(b.z), f3 = unpack_h2(b.w);
        lds4[1024 + 2 * tid + 0] = make_float4(f0.x, f0.y, f1.x, f1.y);
        lds4[1024 + 2 * tid + 1] = make_float4(f2.x, f2.y, f3.x, f3.y);
    }
}

// tier-1 detect: wave 0, one dwordx4 per lane over the compact tag region
__device__ __forceinline__ void detect_tags(const uint32_t* __restrict__ tagbase,
                                            unsigned tt, int tid) {
    if (tid < 64) {
        const uint32_t* qp = tagbase + 4 * tid;
        u32x4 s;
        for (;;) {
            asm volatile("global_load_dwordx4 %0, %1, off sc0 sc1\n\t"
                         "s_waitcnt vmcnt(0)"
                         : "=&v"(s) : "v"(qp) : "memory");
            const bool ok = (s.x == tt) && (s.y == tt) && (s.z == tt) && (s.w == tt);
            if (__all(ok)) break;
            __builtin_amdgcn_s_sleep(1);
        }
    }
}

__global__ __launch_bounds__(NT) void esn_loop(const float* __restrict__ x,
                                               const float* __restrict__ Win,
                                               const float* __restrict__ Wout_w,
                                               const float* __restrict__ Wout_b,
                                               const uint32_t* __restrict__ packed,
                                               uint32_t* __restrict__ pairs,
                                               uint32_t* __restrict__ tags,
                                               float* __restrict__ out) {
    __shared__ float lds_h[RES];
    __shared__ __align__(16) unsigned short hnew16[ROWS_PER_BLOCK];
    __shared__ float lds_red[NT / 64][3];
    __shared__ float lds_x[TSTEPS * 3];

    const int tid = threadIdx.x;
    const int bid = blockIdx.x;
    const int li  = tid & (LPR - 1);
    const int rlocal = tid >> 4;
    const int row = bid * ROWS_PER_BLOCK + rlocal;
    const bool leader = (li == 0);

    __builtin_amdgcn_fence(__ATOMIC_ACQUIRE, "agent");

    for (int i = tid; i < TSTEPS * 3; i += NT) lds_x[i] = x[i];

    // W row slice pre-decoded into register arrays: val f32 + idx
    float wval[SLOTS];
    int   widx[SLOTS];
    {
        const uint4* prow = ((const uint4*)packed) + (size_t)row * (ROW_DW / 4);
#pragma unroll
        for (int i = 0; i < PW_ITERS; ++i) {
            const uint4 p = prow[i * LPR + li];
            wval[i * 4 + 0] = __uint_as_float(p.x); widx[i * 4 + 0] = (int)(p.x & 8191u);
            wval[i * 4 + 1] = __uint_as_float(p.y); widx[i * 4 + 1] = (int)(p.y & 8191u);
            wval[i * 4 + 2] = __uint_as_float(p.z); widx[i * 4 + 2] = (int)(p.z & 8191u);
            wval[i * 4 + 3] = __uint_as_float(p.w); widx[i * 4 + 3] = (int)(p.w & 8191u);
        }
    }

    float win0 = 0.f, win1 = 0.f, win2 = 0.f;
    if (leader) {
        win0 = Win[row * 3 + 0];
        win1 = Win[row * 3 + 1];
        win2 = Win[row * 3 + 2];
    }
    __syncthreads();   // lds_x ready

    float4* const lds4 = (float4*)lds_h;

    for (int t = 0; t < TSTEPS; ++t) {
        float bias = 0.f;
        if (leader)
            bias = win0 * lds_x[t * 3 + 0] + win1 * lds_x[t * 3 + 1] + win2 * lds_x[t * 3 + 2];

        if (t == 0) {
            const float4 z4 = make_float4(0.f, 0.f, 0.f, 0.f);
            for (int i = tid; i < RES / 4; i += NT) lds4[i] = z4;
            __syncthreads();
        } else {
            detect_tags(tags + (size_t)t * NB, (unsigned)t, tid);
            __syncthreads();
            stage_pairs(pairs + (size_t)t * (RES / 2), tid, lds_h);
            __syncthreads();
        }

        // ---- sparse dot: bank-exact schedule, pre-decoded registers ----
        float a0 = 0.f, a1 = 0.f, a2 = 0.f, a3 = 0.f;
#pragma unroll
        for (int s = 0; s < SLOTS; s += 4) {
            a0 += wval[s + 0] * lds_h[widx[s + 0]];
            a1 += wval[s + 1] * lds_h[widx[s + 1]];
            a2 += wval[s + 2] * lds_h[widx[s + 2]];
            a3 += wval[s + 3] * lds_h[widx[s + 3]];
        }
        float acc = (a0 + a1) + (a2 + a3);
#pragma unroll
        for (int off = LPR / 2; off >= 1; off >>= 1)
            acc += __shfl_xor(acc, off, LPR);

        if (leader) {
            const float h = tanhf(acc + bias);
            hnew16[rlocal] = __half_as_ushort(__float2half_rn(h));
        }
        __syncthreads();   // gathers done; hnew16 ready; lds_h free

        // ---- publish: wave 1 lanes 64..67 store 64B pairs, drain, lane 64 tags ----
        if (tid >= 64 && tid < 68) {
            const int q = tid - 64;
            u32x4 v = *(const u32x4*)&hnew16[q * 8];
            uint32_t* dst = &pairs[(size_t)(t + 1) * (RES / 2) + bid * 16 + q * 4];
            asm volatile("global_store_dwordx4 %0, %1, off sc0 sc1\n\t"
                         "s_waitcnt vmcnt(0)"
                         :: "v"(dst), "v"(v) : "memory");
            if (q == 0) {
                uint32_t* tdst = &tags[(size_t)(t + 1) * NB + bid];
                const uint32_t tv = (uint32_t)(t + 1);
                asm volatile("global_store_dword %0, %1, off sc0 sc1"
                             :: "v"(tdst), "v"(tv) : "memory");
            }
        }
        // no barrier: next iteration's post-detect barrier guards lds_h/hnew16 reuse
    }

    // ---- epilogue: y_t = Wout_w @ h_{t+1} + b ----
    const float b0 = Wout_b[0], b1 = Wout_b[1], b2 = Wout_b[2];
    for (int pass = 0; pass < TSTEPS / NB; ++pass) {
        const int tout = bid * (TSTEPS / NB) + pass;
        detect_tags(tags + (size_t)(tout + 1) * NB, (unsigned)(tout + 1), tid);
        __syncthreads();
        stage_pairs(pairs + (size_t)(tout + 1) * (RES / 2), tid, lds_h);
        __syncthreads();
        float s0 = 0.f, s1 = 0.f, s2 = 0.f;
        for (int i = tid; i < RES; i += NT) {
            const float hv = lds_h[i];
            s0 += Wout_w[i] * hv;
            s1 += Wout_w[RES + i] * hv;
            s2 += Wout_w[2 * RES + i] * hv;
        }
#pragma unroll
        for (int off = 32; off >= 1; off >>= 1) {
            s0 += __shfl_xor(s0, off, 64);
            s1 += __shfl_xor(s1, off, 64);
            s2 += __shfl_xor(s2, off, 64);
        }
        const int wv = tid >> 6;
        if ((tid & 63) == 0) { lds_red[wv][0] = s0; lds_red[wv][1] = s1; lds_red[wv][2] = s2; }
        __syncthreads();
        if (tid < 3) {
            float sum = 0.f;
            for (int w = 0; w < NT / 64; ++w) sum += lds_red[w][tid];
            out[tout * 3 + tid] = sum + (tid == 0 ? b0 : (tid == 1 ? b1 : b2));
        }
        __syncthreads();
    }
}

extern "C" void kernel_launch(void* const* d_in, const int* in_sizes, int n_in,
                              void* d_out, int out_size, void* d_ws, size_t ws_size,
                              hipStream_t stream) {
    const float* x      = (const float*)d_in[0];
    const float* Win    = (const float*)d_in[1];
    const float* W      = (const float*)d_in[2];
    const float* Wout_w = (const float*)d_in[3];
    const float* Wout_b = (const float*)d_in[4];

    uint8_t* ws = (uint8_t*)d_ws;
    uint32_t* packed = (uint32_t*)(ws + WS_PACKED_OFF);
    uint32_t* pairs  = (uint32_t*)(ws + WS_PAIRS_OFF);
    uint32_t* tags   = (uint32_t*)(ws + WS_TAGS_OFF);
    float*    out    = (float*)d_out;

    // zero tags (tag 0 never matches any step >= 1); pairs gated by tags
    (void)hipMemsetAsync(tags, 0, TAGS_BYTES, stream);
    esn_compress<<<dim3(RES / 4), dim3(256), 0, stream>>>(W, packed);

    void* args[] = { (void*)&x, (void*)&Win, (void*)&Wout_w, (void*)&Wout_b,
                     (void*)&packed, (void*)&pairs, (void*)&tags, (void*)&out };
    (void)hipLaunchCooperativeKernel((void*)esn_loop, dim3(NB), dim3(NT), args, 0u, stream);
}

// Round 13
// 1840.775 us; speedup vs baseline: 1.5037x; 1.5037x over previous
//
#include <hip/hip_runtime.h>
#include <hip/hip_fp16.h>
#include <stdint.h>

#define RES 8192
#define TSTEPS 512
#define NB 256
#define NT 512
#define ROWS_PER_BLOCK 32
#define LPR 16                           // lanes per row
#define SLOTS 72                         // 64 aligned (2 bank-rings) + 8 tail
#define PW_ITERS (SLOTS / 4)             // 18 uint4 per lane
#define ROW_DW (SLOTS * LPR)             // 1152 dwords per packed row
#define OVF_CAP 24

typedef uint32_t u32x4 __attribute__((ext_vector_type(4)));

// workspace layout (bytes)
#define WS_PACKED_OFF   0u
#define WS_HSEQ_OFF     37748736u                    // 8192*1152*4
#define HSEQ_BYTES      16809984u                    // 513*8192*4

// entry encoding: e = (val19 << 13) | col13, bank = col & 31.
// decode: val = as_float(e) (13 low mantissa bits col-garbage, rel err 2^-10), idx = e & 8191
//
// Fully parallel compress: within a 64-col chunk, lane L's column has bank L&31 by
// construction -> rank-within-bank via register counters + ballot, no serial scans.
// Placement (column order per bank) is IDENTICAL to the previous serial version.
__global__ __launch_bounds__(256) void esn_compress(const float* __restrict__ W,
                                                    uint32_t* __restrict__ packed) {
    __shared__ uint32_t grid[4][LPR][SLOTS];
    __shared__ uint32_t ovf[4][32][OVF_CAP];

    const int wave = threadIdx.x >> 6;
    const int lane = threadIdx.x & 63;
    const int row  = blockIdx.x * 4 + wave;
    const float* wrow = W + (size_t)row * RES;
    uint32_t* prow = packed + (size_t)row * ROW_DW;
    const unsigned b = (unsigned)(lane & 31);

    // ---- prefill grid with bank-correct pads (val=0 denormal) ----
    for (int d = lane; d < LPR * SLOTS; d += 64) {
        const int li = d / SLOTS;
        const int sl = d % SLOTS;
        const unsigned rot = (((unsigned)row & 1u) << 4) | (unsigned)li;
        grid[wave][li][sl] = (sl < 64) ? ((rot + (unsigned)sl) & 31u) : 0u;
    }

    // ---- single parallel pass: rank via ballot + per-lane bank counters ----
    unsigned cnt = 0;                                  // lane b (<32) counts bank b
    for (int chunk = 0; chunk < RES / 64; ++chunk) {
        const int c = chunk * 64 + lane;
        const float v = wrow[c];
        const bool nz = (v != 0.0f);
        const unsigned long long m = __ballot(nz);
        const unsigned base = (unsigned)__shfl((int)cnt, (int)b, 64);
        const unsigned i = base + ((lane >= 32) ? (unsigned)((m >> (lane - 32)) & 1ull) : 0u);
        if (nz) {
            const uint32_t bb = (__float_as_uint(v) + 0x1000u) & 0xFFFFE000u;
            const uint32_t e = bb | (uint32_t)c;
            if (i < 32u) {
                const unsigned li = i & 15u;
                const unsigned j  = i >> 4;
                const unsigned rot = (((unsigned)row & 1u) << 4) | li;
                const unsigned s = j * 32u + ((b - rot) & 31u);
                grid[wave][li][s] = e;
            } else if (i < 32u + OVF_CAP) {
                ovf[wave][b][i - 32u] = e;
            }
        }
        if (lane < 32)
            cnt += (unsigned)((m >> lane) & 1ull) + (unsigned)((m >> (lane + 32)) & 1ull);
    }

    // ---- overflow -> tail: exclusive scan of per-bank excess over lanes 0..31 ----
    unsigned exc = 0;
    if (lane < 32) exc = (cnt > 32u) ? (cnt - 32u) : 0u;
    if (exc > OVF_CAP) exc = OVF_CAP;
    unsigned run = exc;
#pragma unroll
    for (int o = 1; o < 32; o <<= 1) {
        const unsigned vv = (unsigned)__shfl_up((int)run, o, 64);
        if ((lane & 31) >= o) run += vv;
    }
    const unsigned tb = run - exc;                     // exclusive prefix
    if (lane < 32) {
        for (unsigned j = 0; j < exc; ++j) {
            const unsigned q = tb + j;
            if (q < 128u) grid[wave][q & 15u][64u + (q >> 4)] = ovf[wave][lane][j];
        }
    }
    __syncthreads();

    // ---- write out; reader maps uint4 #i, lane li, comp c -> slot 4i+c ----
    for (int d = lane; d < ROW_DW; d += 64) {
        const int li = (d & 63) >> 2;
        const int sl = ((d >> 6) << 2) | (d & 3);
        prow[d] = grid[wave][li][sl];
    }
}

// bulk tagged stage: 4 x dwordx4 LLC loads in ONE asm block (single vmcnt wait per
// round); verify all 16 tags; unpack fp16 payloads into lds_h. Typically 1 round.
__device__ __forceinline__ void stage_tagged(const uint32_t* __restrict__ base,
                                             unsigned tt, int tid, float* lds_h) {
    const uint32_t* p0 = base + (size_t)(tid         ) * 4;
    const uint32_t* p1 = base + (size_t)(tid + 1 * NT) * 4;
    const uint32_t* p2 = base + (size_t)(tid + 2 * NT) * 4;
    const uint32_t* p3 = base + (size_t)(tid + 3 * NT) * 4;
    u32x4 g0, g1, g2, g3;
    for (;;) {
        asm volatile("global_load_dwordx4 %0, %4, off sc0 sc1\n\t"
                     "global_load_dwordx4 %1, %5, off sc0 sc1\n\t"
                     "global_load_dwordx4 %2, %6, off sc0 sc1\n\t"
                     "global_load_dwordx4 %3, %7, off sc0 sc1\n\t"
                     "s_waitcnt vmcnt(0)"
                     : "=&v"(g0), "=&v"(g1), "=&v"(g2), "=&v"(g3)
                     : "v"(p0), "v"(p1), "v"(p2), "v"(p3)
                     : "memory");
        const bool ok =
            (g0.x >> 16) == tt && (g0.y >> 16) == tt && (g0.z >> 16) == tt && (g0.w >> 16) == tt &&
            (g1.x >> 16) == tt && (g1.y >> 16) == tt && (g1.z >> 16) == tt && (g1.w >> 16) == tt &&
            (g2.x >> 16) == tt && (g2.y >> 16) == tt && (g2.z >> 16) == tt && (g2.w >> 16) == tt &&
            (g3.x >> 16) == tt && (g3.y >> 16) == tt && (g3.z >> 16) == tt && (g3.w >> 16) == tt;
        if (ok) break;
        __builtin_amdgcn_s_sleep(1);
    }
    float4* const lds4 = (float4*)lds_h;
    lds4[tid         ] = make_float4(__half2float(__ushort_as_half((unsigned short)g0.x)),
                                     __half2float(__ushort_as_half((unsigned short)g0.y)),
                                     __half2float(__ushort_as_half((unsigned short)g0.z)),
                                     __half2float(__ushort_as_half((unsigned short)g0.w)));
    lds4[tid + 1 * NT] = make_float4(__half2float(__ushort_as_half((unsigned short)g1.x)),
                                     __half2float(__ushort_as_half((unsigned short)g1.y)),
                                     __half2float(__ushort_as_half((unsigned short)g1.z)),
                                     __half2float(__ushort_as_half((unsigned short)g1.w)));
    lds4[tid + 2 * NT] = make_float4(__half2float(__ushort_as_half((unsigned short)g2.x)),
                                     __half2float(__ushort_as_half((unsigned short)g2.y)),
                                     __half2float(__ushort_as_half((unsigned short)g2.z)),
                                     __half2float(__ushort_as_half((unsigned short)g2.w)));
    lds4[tid + 3 * NT] = make_float4(__half2float(__ushort_as_half((unsigned short)g3.x)),
                                     __half2float(__ushort_as_half((unsigned short)g3.y)),
                                     __half2float(__ushort_as_half((unsigned short)g3.z)),
                                     __half2float(__ushort_as_half((unsigned short)g3.w)));
}

__global__ __launch_bounds__(NT) void esn_loop(const float* __restrict__ x,
                                               const float* __restrict__ Win,
                                               const float* __restrict__ Wout_w,
                                               const float* __restrict__ Wout_b,
                                               const uint32_t* __restrict__ packed,
                                               uint32_t* __restrict__ hseq,
                                               float* __restrict__ out) {
    __shared__ float lds_h[RES];
    __shared__ uint32_t lds_hnew[ROWS_PER_BLOCK];   // tagged packed words
    __shared__ float lds_red[NT / 64][3];
    __shared__ float lds_x[TSTEPS * 3];

    const int tid = threadIdx.x;
    const int bid = blockIdx.x;
    const int li  = tid & (LPR - 1);
    const int rlocal = tid >> 4;
    const int row = bid * ROWS_PER_BLOCK + rlocal;
    const bool leader = (li == 0);

    __builtin_amdgcn_fence(__ATOMIC_ACQUIRE, "agent");

    for (int i = tid; i < TSTEPS * 3; i += NT) lds_x[i] = x[i];

    // W row slice into registers: 18 x uint4 = 72 VGPRs
    uint4 pw[PW_ITERS];
    {
        const uint4* prow = ((const uint4*)packed) + (size_t)row * (ROW_DW / 4);
#pragma unroll
        for (int i = 0; i < PW_ITERS; ++i) pw[i] = prow[i * LPR + li];
    }

    float win0 = 0.f, win1 = 0.f, win2 = 0.f;
    if (leader) {
        win0 = Win[row * 3 + 0];
        win1 = Win[row * 3 + 1];
        win2 = Win[row * 3 + 2];
    }
    __syncthreads();   // lds_x ready

    float4* const lds4 = (float4*)lds_h;

    for (int t = 0; t < TSTEPS; ++t) {
        float bias = 0.f;
        if (leader)
            bias = win0 * lds_x[t * 3 + 0] + win1 * lds_x[t * 3 + 1] + win2 * lds_x[t * 3 + 2];

        if (t == 0) {
            const float4 z4 = make_float4(0.f, 0.f, 0.f, 0.f);
            for (int i = tid; i < RES / 4; i += NT) lds4[i] = z4;
            __syncthreads();
        } else {
            // ---- tier-1 detect: wave 0 samples word 31 of each producer block
            //      (publish is one cache line -> word 31 present => line present) ----
            if (tid < 64) {
                const unsigned tt = (unsigned)t;
                const uint32_t* sb = hseq + (size_t)t * RES + 31;
                const uint32_t* q0 = sb + (size_t)(tid        ) * 32;
                const uint32_t* q1 = sb + (size_t)(tid +  64) * 32;
                const uint32_t* q2 = sb + (size_t)(tid + 128) * 32;
                const uint32_t* q3 = sb + (size_t)(tid + 192) * 32;
                uint32_t s0, s1, s2, s3;
                for (;;) {
                    asm volatile("global_load_dword %0, %4, off sc0 sc1\n\t"
                                 "global_load_dword %1, %5, off sc0 sc1\n\t"
                                 "global_load_dword %2, %6, off sc0 sc1\n\t"
                                 "global_load_dword %3, %7, off sc0 sc1\n\t"
                                 "s_waitcnt vmcnt(0)"
                                 : "=&v"(s0), "=&v"(s1), "=&v"(s2), "=&v"(s3)
                                 : "v"(q0), "v"(q1), "v"(q2), "v"(q3)
                                 : "memory");
                    const bool ok = (s0 >> 16) == tt && (s1 >> 16) == tt &&
                                    (s2 >> 16) == tt && (s3 >> 16) == tt;
                    if (__all(ok)) break;
                    __builtin_amdgcn_s_sleep(1);
                }
            }
            __syncthreads();
            // ---- tier-2: bulk tagged transfer (self-verifying, ~1 round) ----
            stage_tagged(hseq + (size_t)t * RES, (unsigned)t, tid, lds_h);
            __syncthreads();
        }

        // ---- sparse dot: bank-exact schedule, direct-value decode ----
        float a0 = 0.f, a1 = 0.f, a2 = 0.f, a3 = 0.f;
#pragma unroll
        for (int i = 0; i < PW_ITERS; ++i) {
            const uint4 p = pw[i];
            a0 += __uint_as_float(p.x) * lds_h[p.x & 8191u];
            a1 += __uint_as_float(p.y) * lds_h[p.y & 8191u];
            a2 += __uint_as_float(p.z) * lds_h[p.z & 8191u];
            a3 += __uint_as_float(p.w) * lds_h[p.w & 8191u];
        }
        float acc = (a0 + a1) + (a2 + a3);
#pragma unroll
        for (int off = LPR / 2; off >= 1; off >>= 1)
            acc += __shfl_xor(acc, off, LPR);

        if (leader) {
            const float h = tanhf(acc + bias);
            lds_hnew[rlocal] = ((uint32_t)(t + 1) << 16) |
                               (uint32_t)__half_as_ushort(__float2half_rn(h));
        }
        __syncthreads();   // gathers done; lds_hnew ready; lds_h free

        // ---- publish h_{t+1}: 32 tagged words = ONE cache line, fire-and-forget ----
        if (tid < ROWS_PER_BLOCK) {
            __hip_atomic_store(&hseq[(size_t)(t + 1) * RES + bid * ROWS_PER_BLOCK + tid],
                               lds_hnew[tid],
                               __ATOMIC_RELAXED, __HIP_MEMORY_SCOPE_AGENT);
        }
        // no barrier: next iteration's post-detect barrier guards lds_h/lds_hnew reuse
    }

    // ---- epilogue: y_t = Wout_w @ h_{t+1} + b; staging self-synchronizes via tags ----
    const float b0 = Wout_b[0], b1 = Wout_b[1], b2 = Wout_b[2];
    for (int pass = 0; pass < TSTEPS / NB; ++pass) {
        const int tout = bid * (TSTEPS / NB) + pass;
        __syncthreads();
        stage_tagged(hseq + (size_t)(tout + 1) * RES, (unsigned)(tout + 1), tid, lds_h);
        __syncthreads();
        float s0 = 0.f, s1 = 0.f, s2 = 0.f;
        for (int i = tid; i < RES; i += NT) {
            const float hv = lds_h[i];
            s0 += Wout_w[i] * hv;
            s1 += Wout_w[RES + i] * hv;
            s2 += Wout_w[2 * RES + i] * hv;
        }
#pragma unroll
        for (int off = 32; off >= 1; off >>= 1) {
            s0 += __shfl_xor(s0, off, 64);
            s1 += __shfl_xor(s1, off, 64);
            s2 += __shfl_xor(s2, off, 64);
        }
        const int wv = tid >> 6;
        if ((tid & 63) == 0) { lds_red[wv][0] = s0; lds_red[wv][1] = s1; lds_red[wv][2] = s2; }
        __syncthreads();
        if (tid < 3) {
            float sum = 0.f;
            for (int w = 0; w < NT / 64; ++w) sum += lds_red[w][tid];
            out[tout * 3 + tid] = sum + (tid == 0 ? b0 : (tid == 1 ? b1 : b2));
        }
    }
}

extern "C" void kernel_launch(void* const* d_in, const int* in_sizes, int n_in,
                              void* d_out, int out_size, void* d_ws, size_t ws_size,
                              hipStream_t stream) {
    const float* x      = (const float*)d_in[0];
    const float* Win    = (const float*)d_in[1];
    const float* W      = (const float*)d_in[2];
    const float* Wout_w = (const float*)d_in[3];
    const float* Wout_b = (const float*)d_in[4];

    uint8_t* ws = (uint8_t*)d_ws;
    uint32_t* packed = (uint32_t*)(ws + WS_PACKED_OFF);
    uint32_t* hseq   = (uint32_t*)(ws + WS_HSEQ_OFF);
    float*    out    = (float*)d_out;

    // zero all tags so no stale/garbage word can false-match (tag 0 != any t>=1)
    (void)hipMemsetAsync(hseq, 0, HSEQ_BYTES, stream);
    esn_compress<<<dim3(RES / 4), dim3(256), 0, stream>>>(W, packed);

    void* args[] = { (void*)&x, (void*)&Win, (void*)&Wout_w, (void*)&Wout_b,
                     (void*)&packed, (void*)&hseq, (void*)&out };
    (void)hipLaunchCooperativeKernel((void*)esn_loop, dim3(NB), dim3(NT), args, 0u, stream);
}

// Round 14
// 1798.397 us; speedup vs baseline: 1.5392x; 1.0236x over previous
//
#include <hip/hip_runtime.h>
#include <hip/hip_fp16.h>
#include <stdint.h>

#define RES 8192
#define TSTEPS 512
#define NB 256
#define NT 512
#define ROWS_PER_BLOCK 32
#define LPR 16                           // lanes per row
#define SLOTS 68                         // 64 aligned (2 bank-rings) + 4 tail
#define PW_ITERS (SLOTS / 4)             // 17 uint4 per lane
#define ROW_DW (SLOTS * LPR)             // 1088 dwords per packed row
#define TAIL_CAP 64                      // 4 tail slots x 16 lanes
#define OVF_CAP 24

typedef uint32_t u32x4 __attribute__((ext_vector_type(4)));

// workspace layout (bytes)
#define WS_PACKED_OFF   0u
#define WS_HSEQ_OFF     37748736u                    // > 8192*1088*4, kept from r13
#define HSEQ_BYTES      16809984u                    // 513*8192*4

// entry encoding: e = (val19 << 13) | col13, bank = col & 31.
// decode: val = as_float(e) (13 low mantissa bits col-garbage, rel err 2^-10), idx = e & 8191
__global__ __launch_bounds__(256) void esn_compress(const float* __restrict__ W,
                                                    uint32_t* __restrict__ packed) {
    __shared__ uint32_t grid[4][LPR][SLOTS];
    __shared__ uint32_t ovf[4][32][OVF_CAP];

    const int wave = threadIdx.x >> 6;
    const int lane = threadIdx.x & 63;
    const int row  = blockIdx.x * 4 + wave;
    const float* wrow = W + (size_t)row * RES;
    uint32_t* prow = packed + (size_t)row * ROW_DW;
    const unsigned b = (unsigned)(lane & 31);

    // ---- prefill grid with bank-correct pads (val=0 denormal) ----
    for (int d = lane; d < LPR * SLOTS; d += 64) {
        const int li = d / SLOTS;
        const int sl = d % SLOTS;
        const unsigned rot = (((unsigned)row & 1u) << 4) | (unsigned)li;
        grid[wave][li][sl] = (sl < 64) ? ((rot + (unsigned)sl) & 31u) : 0u;
    }

    // ---- single parallel pass: rank via ballot + per-lane bank counters ----
    unsigned cnt = 0;                                  // lane b (<32) counts bank b
    for (int chunk = 0; chunk < RES / 64; ++chunk) {
        const int c = chunk * 64 + lane;
        const float v = wrow[c];
        const bool nz = (v != 0.0f);
        const unsigned long long m = __ballot(nz);
        const unsigned base = (unsigned)__shfl((int)cnt, (int)b, 64);
        const unsigned i = base + ((lane >= 32) ? (unsigned)((m >> (lane - 32)) & 1ull) : 0u);
        if (nz) {
            const uint32_t bb = (__float_as_uint(v) + 0x1000u) & 0xFFFFE000u;
            const uint32_t e = bb | (uint32_t)c;
            if (i < 32u) {
                const unsigned li = i & 15u;
                const unsigned j  = i >> 4;
                const unsigned rot = (((unsigned)row & 1u) << 4) | li;
                const unsigned s = j * 32u + ((b - rot) & 31u);
                grid[wave][li][s] = e;
            } else if (i < 32u + OVF_CAP) {
                ovf[wave][b][i - 32u] = e;
            }
        }
        if (lane < 32)
            cnt += (unsigned)((m >> lane) & 1ull) + (unsigned)((m >> (lane + 32)) & 1ull);
    }

    // ---- overflow -> tail: exclusive scan of per-bank excess over lanes 0..31 ----
    unsigned exc = 0;
    if (lane < 32) exc = (cnt > 32u) ? (cnt - 32u) : 0u;
    if (exc > OVF_CAP) exc = OVF_CAP;
    unsigned run = exc;
#pragma unroll
    for (int o = 1; o < 32; o <<= 1) {
        const unsigned vv = (unsigned)__shfl_up((int)run, o, 64);
        if ((lane & 31) >= o) run += vv;
    }
    const unsigned tb = run - exc;                     // exclusive prefix
    if (lane < 32) {
        for (unsigned j = 0; j < exc; ++j) {
            const unsigned q = tb + j;
            if (q < TAIL_CAP) grid[wave][q & 15u][64u + (q >> 4)] = ovf[wave][lane][j];
        }
    }
    __syncthreads();

    // ---- write out; reader maps uint4 #i, lane li, comp c -> slot 4i+c ----
    for (int d = lane; d < ROW_DW; d += 64) {
        const int li = (d & 63) >> 2;
        const int sl = ((d >> 6) << 2) | (d & 3);
        prow[d] = grid[wave][li][sl];
    }
}

// bulk tagged stage: 4 x dwordx4 LLC loads in ONE asm block (single vmcnt wait per
// round); verify all 16 tags; unpack fp16 payloads into lds_h. Typically 1 round.
__device__ __forceinline__ void stage_tagged(const uint32_t* __restrict__ base,
                                             unsigned tt, int tid, float* lds_h) {
    const uint32_t* p0 = base + (size_t)(tid         ) * 4;
    const uint32_t* p1 = base + (size_t)(tid + 1 * NT) * 4;
    const uint32_t* p2 = base + (size_t)(tid + 2 * NT) * 4;
    const uint32_t* p3 = base + (size_t)(tid + 3 * NT) * 4;
    u32x4 g0, g1, g2, g3;
    for (;;) {
        asm volatile("global_load_dwordx4 %0, %4, off sc0 sc1\n\t"
                     "global_load_dwordx4 %1, %5, off sc0 sc1\n\t"
                     "global_load_dwordx4 %2, %6, off sc0 sc1\n\t"
                     "global_load_dwordx4 %3, %7, off sc0 sc1\n\t"
                     "s_waitcnt vmcnt(0)"
                     : "=&v"(g0), "=&v"(g1), "=&v"(g2), "=&v"(g3)
                     : "v"(p0), "v"(p1), "v"(p2), "v"(p3)
                     : "memory");
        const bool ok =
            (g0.x >> 16) == tt && (g0.y >> 16) == tt && (g0.z >> 16) == tt && (g0.w >> 16) == tt &&
            (g1.x >> 16) == tt && (g1.y >> 16) == tt && (g1.z >> 16) == tt && (g1.w >> 16) == tt &&
            (g2.x >> 16) == tt && (g2.y >> 16) == tt && (g2.z >> 16) == tt && (g2.w >> 16) == tt &&
            (g3.x >> 16) == tt && (g3.y >> 16) == tt && (g3.z >> 16) == tt && (g3.w >> 16) == tt;
        if (ok) break;
        __builtin_amdgcn_s_sleep(1);
    }
    float4* const lds4 = (float4*)lds_h;
    lds4[tid         ] = make_float4(__half2float(__ushort_as_half((unsigned short)g0.x)),
                                     __half2float(__ushort_as_half((unsigned short)g0.y)),
                                     __half2float(__ushort_as_half((unsigned short)g0.z)),
                                     __half2float(__ushort_as_half((unsigned short)g0.w)));
    lds4[tid + 1 * NT] = make_float4(__half2float(__ushort_as_half((unsigned short)g1.x)),
                                     __half2float(__ushort_as_half((unsigned short)g1.y)),
                                     __half2float(__ushort_as_half((unsigned short)g1.z)),
                                     __half2float(__ushort_as_half((unsigned short)g1.w)));
    lds4[tid + 2 * NT] = make_float4(__half2float(__ushort_as_half((unsigned short)g2.x)),
                                     __half2float(__ushort_as_half((unsigned short)g2.y)),
                                     __half2float(__ushort_as_half((unsigned short)g2.z)),
                                     __half2float(__ushort_as_half((unsigned short)g2.w)));
    lds4[tid + 3 * NT] = make_float4(__half2float(__ushort_as_half((unsigned short)g3.x)),
                                     __half2float(__ushort_as_half((unsigned short)g3.y)),
                                     __half2float(__ushort_as_half((unsigned short)g3.z)),
                                     __half2float(__ushort_as_half((unsigned short)g3.w)));
}

__global__ __launch_bounds__(NT) void esn_loop(const float* __restrict__ x,
                                               const float* __restrict__ Win,
                                               const float* __restrict__ Wout_w,
                                               const float* __restrict__ Wout_b,
                                               const uint32_t* __restrict__ packed,
                                               uint32_t* __restrict__ hseq,
                                               float* __restrict__ out) {
    __shared__ float lds_h[RES];
    __shared__ uint32_t lds_hnew[ROWS_PER_BLOCK];   // tagged packed words
    __shared__ float lds_red[NT / 64][3];
    __shared__ float lds_x[TSTEPS * 3];

    const int tid = threadIdx.x;
    const int bid = blockIdx.x;
    const int li  = tid & (LPR - 1);
    const int rlocal = tid >> 4;
    const int row = bid * ROWS_PER_BLOCK + rlocal;
    const bool leader = (li == 0);

    __builtin_amdgcn_fence(__ATOMIC_ACQUIRE, "agent");

    for (int i = tid; i < TSTEPS * 3; i += NT) lds_x[i] = x[i];

    // W row slice into registers: 17 x uint4 = 68 VGPRs
    uint4 pw[PW_ITERS];
    {
        const uint4* prow = ((const uint4*)packed) + (size_t)row * (ROW_DW / 4);
#pragma unroll
        for (int i = 0; i < PW_ITERS; ++i) pw[i] = prow[i * LPR + li];
    }

    float win0 = 0.f, win1 = 0.f, win2 = 0.f;
    if (leader) {
        win0 = Win[row * 3 + 0];
        win1 = Win[row * 3 + 1];
        win2 = Win[row * 3 + 2];
    }
    __syncthreads();   // lds_x ready

    float4* const lds4 = (float4*)lds_h;

    for (int t = 0; t < TSTEPS; ++t) {
        float bias = 0.f;
        if (leader)
            bias = win0 * lds_x[t * 3 + 0] + win1 * lds_x[t * 3 + 1] + win2 * lds_x[t * 3 + 2];

        if (t == 0) {
            const float4 z4 = make_float4(0.f, 0.f, 0.f, 0.f);
            for (int i = tid; i < RES / 4; i += NT) lds4[i] = z4;
            __syncthreads();
        } else {
            // ---- tier-1 detect: wave 0 samples word 31 of each producer block
            //      (publish is one cache line -> word 31 present => line present).
            //      Tight spin, no s_sleep: the LLC RT is the natural backoff. ----
            if (tid < 64) {
                const unsigned tt = (unsigned)t;
                const uint32_t* sb = hseq + (size_t)t * RES + 31;
                const uint32_t* q0 = sb + (size_t)(tid        ) * 32;
                const uint32_t* q1 = sb + (size_t)(tid +  64) * 32;
                const uint32_t* q2 = sb + (size_t)(tid + 128) * 32;
                const uint32_t* q3 = sb + (size_t)(tid + 192) * 32;
                uint32_t s0, s1, s2, s3;
                for (;;) {
                    asm volatile("global_load_dword %0, %4, off sc0 sc1\n\t"
                                 "global_load_dword %1, %5, off sc0 sc1\n\t"
                                 "global_load_dword %2, %6, off sc0 sc1\n\t"
                                 "global_load_dword %3, %7, off sc0 sc1\n\t"
                                 "s_waitcnt vmcnt(0)"
                                 : "=&v"(s0), "=&v"(s1), "=&v"(s2), "=&v"(s3)
                                 : "v"(q0), "v"(q1), "v"(q2), "v"(q3)
                                 : "memory");
                    const bool ok = (s0 >> 16) == tt && (s1 >> 16) == tt &&
                                    (s2 >> 16) == tt && (s3 >> 16) == tt;
                    if (__all(ok)) break;
                }
            }
            __syncthreads();
            // ---- tier-2: bulk tagged transfer (self-verifying, ~1 round) ----
            stage_tagged(hseq + (size_t)t * RES, (unsigned)t, tid, lds_h);
            __syncthreads();
        }

        // ---- sparse dot: bank-exact schedule, direct-value decode ----
        float a0 = 0.f, a1 = 0.f, a2 = 0.f, a3 = 0.f;
#pragma unroll
        for (int i = 0; i < PW_ITERS; ++i) {
            const uint4 p = pw[i];
            a0 += __uint_as_float(p.x) * lds_h[p.x & 8191u];
            a1 += __uint_as_float(p.y) * lds_h[p.y & 8191u];
            a2 += __uint_as_float(p.z) * lds_h[p.z & 8191u];
            a3 += __uint_as_float(p.w) * lds_h[p.w & 8191u];
        }
        float acc = (a0 + a1) + (a2 + a3);
#pragma unroll
        for (int off = LPR / 2; off >= 1; off >>= 1)
            acc += __shfl_xor(acc, off, LPR);

        if (leader) {
            const float h = tanhf(acc + bias);
            lds_hnew[rlocal] = ((uint32_t)(t + 1) << 16) |
                               (uint32_t)__half_as_ushort(__float2half_rn(h));
        }
        __syncthreads();   // gathers done; lds_hnew ready; lds_h free

        // ---- publish h_{t+1}: 32 tagged words = ONE cache line, fire-and-forget ----
        if (tid < ROWS_PER_BLOCK) {
            __hip_atomic_store(&hseq[(size_t)(t + 1) * RES + bid * ROWS_PER_BLOCK + tid],
                               lds_hnew[tid],
                               __ATOMIC_RELAXED, __HIP_MEMORY_SCOPE_AGENT);
        }
        // no barrier: next iteration's post-detect barrier guards lds_h/lds_hnew reuse
    }

    // ---- epilogue: y_t = Wout_w @ h_{t+1} + b; staging self-synchronizes via tags ----
    const float b0 = Wout_b[0], b1 = Wout_b[1], b2 = Wout_b[2];
    for (int pass = 0; pass < TSTEPS / NB; ++pass) {
        const int tout = bid * (TSTEPS / NB) + pass;
        __syncthreads();
        stage_tagged(hseq + (size_t)(tout + 1) * RES, (unsigned)(tout + 1), tid, lds_h);
        __syncthreads();
        float s0 = 0.f, s1 = 0.f, s2 = 0.f;
        for (int i = tid; i < RES; i += NT) {
            const float hv = lds_h[i];
            s0 += Wout_w[i] * hv;
            s1 += Wout_w[RES + i] * hv;
            s2 += Wout_w[2 * RES + i] * hv;
        }
#pragma unroll
        for (int off = 32; off >= 1; off >>= 1) {
            s0 += __shfl_xor(s0, off, 64);
            s1 += __shfl_xor(s1, off, 64);
            s2 += __shfl_xor(s2, off, 64);
        }
        const int wv = tid >> 6;
        if ((tid & 63) == 0) { lds_red[wv][0] = s0; lds_red[wv][1] = s1; lds_red[wv][2] = s2; }
        __syncthreads();
        if (tid < 3) {
            float sum = 0.f;
            for (int w = 0; w < NT / 64; ++w) sum += lds_red[w][tid];
            out[tout * 3 + tid] = sum + (tid == 0 ? b0 : (tid == 1 ? b1 : b2));
        }
    }
}

extern "C" void kernel_launch(void* const* d_in, const int* in_sizes, int n_in,
                              void* d_out, int out_size, void* d_ws, size_t ws_size,
                              hipStream_t stream) {
    const float* x      = (const float*)d_in[0];
    const float* Win    = (const float*)d_in[1];
    const float* W      = (const float*)d_in[2];
    const float* Wout_w = (const float*)d_in[3];
    const float* Wout_b = (const float*)d_in[4];

    uint8_t* ws = (uint8_t*)d_ws;
    uint32_t* packed = (uint32_t*)(ws + WS_PACKED_OFF);
    uint32_t* hseq   = (uint32_t*)(ws + WS_HSEQ_OFF);
    float*    out    = (float*)d_out;

    // zero all tags so no stale/garbage word can false-match (tag 0 != any t>=1)
    (void)hipMemsetAsync(hseq, 0, HSEQ_BYTES, stream);
    esn_compress<<<dim3(RES / 4), dim3(256), 0, stream>>>(W, packed);

    void* args[] = { (void*)&x, (void*)&Win, (void*)&Wout_w, (void*)&Wout_b,
                     (void*)&packed, (void*)&hseq, (void*)&out };
    (void)hipLaunchCooperativeKernel((void*)esn_loop, dim3(NB), dim3(NT), args, 0u, stream);
}